// Round 2
// baseline (905.753 us; speedup 1.0000x reference)
//
#include <hip/hip_runtime.h>

typedef unsigned short ushort_t;
typedef __attribute__((ext_vector_type(8))) short bf16x8;
typedef __attribute__((ext_vector_type(4))) float f32x4;

#define C_DIM 128
#define K_CB  1024
#define N_ROWS 131072
#define NUMEL (N_ROWS * C_DIM)
#define XPAD 132
#define TAU 1.5e-4f

#define GLOAD16(gp, lp) __builtin_amdgcn_global_load_lds( \
    (const __attribute__((address_space(1))) unsigned int*)(gp), \
    (__attribute__((address_space(3))) unsigned int*)(lp), 16, 0, 0)

__device__ __forceinline__ ushort_t f2bf(float x) {
    union { float f; unsigned int u; } a; a.f = x;
    unsigned int r = a.u + 0x7fffu + ((a.u >> 16) & 1u);
    return (ushort_t)(r >> 16);
}
__device__ __forceinline__ float bf2f(ushort_t h) {
    union { unsigned int u; float f; } a; a.u = ((unsigned int)h) << 16;
    return a.f;
}

// ---------- prep codebook: bn (r1 arithmetic), B hi/lo planes, zero flag count ----------
__global__ void prep_cb_kernel(const float* __restrict__ cb, float* __restrict__ bn,
                               ushort_t* __restrict__ Bpl, int* __restrict__ count) {
    int k = blockIdx.x * 256 + threadIdx.x;
    if (blockIdx.x == 0 && threadIdx.x == 0) count[0] = 0;
    if (k >= K_CB) return;
    const float4* row = reinterpret_cast<const float4*>(cb) + k * 32;
    float s = 0.f;
    #pragma unroll
    for (int i = 0; i < 32; ++i) {
        float4 v = row[i];
        s = fmaf(v.x, v.x, s); s = fmaf(v.y, v.y, s);
        s = fmaf(v.z, v.z, s); s = fmaf(v.w, v.w, s);
    }
    bn[k] = s;
    const float* rf = cb + k * 128;
    #pragma unroll
    for (int c = 0; c < 128; ++c) {
        float x = rf[c];
        ushort_t h = f2bf(x);
        ushort_t l = f2bf(x - bf2f(h));
        Bpl[k * 256 + c] = h;
        Bpl[k * 256 + 128 + c] = l;
    }
}

// ---------- prep x: transpose-gather, xn (r1 arithmetic), A hi/lo planes ----------
__global__ void prep_x_kernel(const float* __restrict__ in, float* __restrict__ xn,
                              ushort_t* __restrict__ Apl) {
    __shared__ float xs[64 * XPAD];
    const int tid = threadIdx.x;
    const int n0 = blockIdx.x * 64;
    {
        const int base = (n0 >> 14) * (C_DIM * 16384) + (n0 & 16383);
        #pragma unroll
        for (int i = 0; i < 8; ++i) {
            int idx = tid + i * 256;
            int nl = idx & 63;
            int c4 = idx >> 6;
            float4 v;
            v.x = in[base + (c4 * 4 + 0) * 16384 + nl];
            v.y = in[base + (c4 * 4 + 1) * 16384 + nl];
            v.z = in[base + (c4 * 4 + 2) * 16384 + nl];
            v.w = in[base + (c4 * 4 + 3) * 16384 + nl];
            *reinterpret_cast<float4*>(&xs[nl * XPAD + c4 * 4]) = v;
        }
    }
    __syncthreads();
    if (tid < 64) {
        const float* xr = &xs[tid * XPAD];
        float s = 0.f;
        #pragma unroll
        for (int c = 0; c < C_DIM; ++c) s = fmaf(xr[c], xr[c], s);
        xn[n0 + tid] = s;
    }
    #pragma unroll
    for (int i = 0; i < 8; ++i) {
        int idx = tid + i * 256;
        int row = idx >> 5;
        int c4 = idx & 31;
        float4 v = *reinterpret_cast<const float4*>(&xs[row * XPAD + c4 * 4]);
        ushort_t h0 = f2bf(v.x), h1 = f2bf(v.y), h2 = f2bf(v.z), h3 = f2bf(v.w);
        ushort4 H; H.x = h0; H.y = h1; H.z = h2; H.w = h3;
        ushort4 L;
        L.x = f2bf(v.x - bf2f(h0)); L.y = f2bf(v.y - bf2f(h1));
        L.z = f2bf(v.z - bf2f(h2)); L.w = f2bf(v.w - bf2f(h3));
        size_t rb = (size_t)(n0 + row) * 256;
        *reinterpret_cast<ushort4*>(&Apl[rb + c4 * 4]) = H;
        *reinterpret_cast<ushort4*>(&Apl[rb + 128 + c4 * 4]) = L;
    }
}

// ---------- main MFMA distance GEMM + argmin + margin flags ----------
__launch_bounds__(256, 2)
__global__ void gemm_argmin_kernel(const ushort_t* __restrict__ Apl,
                                   const ushort_t* __restrict__ Bpl,
                                   const float* __restrict__ bn,
                                   const float* __restrict__ xn,
                                   float* __restrict__ idx_out,
                                   int* __restrict__ flags,
                                   int* __restrict__ count) {
    __shared__ ushort_t A_lds[64 * 256];     // 32KB: [row][256] hi|lo planes
    __shared__ ushort_t Bb[2][128 * 64];     // 2x16KB: [cbrow][64]
    __shared__ float bn_s[K_CB];
    __shared__ float xn_s[64];
    __shared__ float m_b1[4][64];
    __shared__ float m_b2[4][64];
    __shared__ int   m_i1[4][64];

    const int tid = threadIdx.x;
    const int w = tid >> 6, lane = tid & 63;
    const int g4 = lane >> 4, l15 = lane & 15;
    const int m0 = blockIdx.x * 64;

    f32x4 acc[4][2];
    const f32x4 zz = {0.f, 0.f, 0.f, 0.f};
    #pragma unroll
    for (int mi = 0; mi < 4; ++mi)
        #pragma unroll
        for (int ni = 0; ni < 2; ++ni) acc[mi][ni] = zz;

    float b1[16], b2[16]; int i1[16];
    #pragma unroll
    for (int sl = 0; sl < 16; ++sl) { b1[sl] = 3.4e38f; b2[sl] = 3.4e38f; i1[sl] = 0; }

    // prologue: stage A tile (rows m0..m0+63, 256 bf16 each), B chunk 0, bn/xn
    #pragma unroll
    for (int i = 0; i < 8; ++i) {
        int row = w * 16 + i * 2 + (lane >> 5);
        const ushort_t* g = Apl + (size_t)(m0 + row) * 256 + (lane & 31) * 8;
        GLOAD16(g, &A_lds[(w * 16 + i * 2) * 256]);
    }
    #pragma unroll
    for (int i = 0; i < 4; ++i) {
        int r = w * 32 + i * 8 + (lane >> 3);
        const ushort_t* g = Bpl + (size_t)r * 256 + (lane & 7) * 8;
        GLOAD16(g, &Bb[0][(w * 32 + i * 8) * 64]);
    }
    for (int i = tid; i < K_CB; i += 256) bn_s[i] = bn[i];
    if (tid < 64) xn_s[tid] = xn[m0 + tid];
    __syncthreads();

    for (int t = 0; t < 48; ++t) {
        const int c = t % 6, kt = t / 6, buf = t & 1;
        if (t + 1 < 48) {
            const int c2 = (t + 1) % 6, kt2 = (t + 1) / 6, nb = (t + 1) & 1;
            const int bt2 = ((c2 >= 2 && c2 < 4) ? 128 : 0) + (c2 & 1) * 64;
            #pragma unroll
            for (int i = 0; i < 4; ++i) {
                int r = w * 32 + i * 8 + (lane >> 3);
                const ushort_t* g = Bpl + (size_t)(kt2 * 128 + r) * 256 + bt2 + (lane & 7) * 8;
                GLOAD16(g, &Bb[nb][(w * 32 + i * 8) * 64]);
            }
        }
        const int at = ((c >= 4) ? 128 : 0) + (c & 1) * 64;

        bf16x8 af[4][2], bfr[2][2];
        #pragma unroll
        for (int mi = 0; mi < 4; ++mi)
            #pragma unroll
            for (int kk = 0; kk < 2; ++kk)
                af[mi][kk] = *reinterpret_cast<const bf16x8*>(
                    &A_lds[(mi * 16 + l15) * 256 + at + kk * 32 + g4 * 8]);
        #pragma unroll
        for (int ni = 0; ni < 2; ++ni)
            #pragma unroll
            for (int kk = 0; kk < 2; ++kk)
                bfr[ni][kk] = *reinterpret_cast<const bf16x8*>(
                    &Bb[buf][(w * 32 + ni * 16 + l15) * 64 + kk * 32 + g4 * 8]);
        #pragma unroll
        for (int mi = 0; mi < 4; ++mi)
            #pragma unroll
            for (int ni = 0; ni < 2; ++ni) {
                acc[mi][ni] = __builtin_amdgcn_mfma_f32_16x16x32_bf16(af[mi][0], bfr[ni][0], acc[mi][ni], 0, 0, 0);
                acc[mi][ni] = __builtin_amdgcn_mfma_f32_16x16x32_bf16(af[mi][1], bfr[ni][1], acc[mi][ni], 0, 0, 0);
            }

        if (c == 5) {
            #pragma unroll
            for (int mi = 0; mi < 4; ++mi) {
                #pragma unroll
                for (int r = 0; r < 4; ++r) {
                    float xv = xn_s[mi * 16 + g4 * 4 + r];
                    #pragma unroll
                    for (int ni = 0; ni < 2; ++ni) {
                        int n = kt * 128 + w * 32 + ni * 16 + l15;
                        float s = fmaf(-2.0f, acc[mi][ni][r], xv + bn_s[n]);
                        int sl = mi * 4 + r;
                        if (s < b1[sl]) { b2[sl] = b1[sl]; b1[sl] = s; i1[sl] = n; }
                        else if (s < b2[sl]) b2[sl] = s;
                    }
                }
                #pragma unroll
                for (int ni = 0; ni < 2; ++ni) acc[mi][ni] = zz;
            }
        }
        __syncthreads();
    }

    // cross-lane argmin merge within each 16-lane col group
    #pragma unroll
    for (int sl = 0; sl < 16; ++sl) {
        float v1 = b1[sl], v2 = b2[sl]; int ix = i1[sl];
        #pragma unroll
        for (int m = 1; m < 16; m <<= 1) {
            float o1 = __shfl_xor(v1, m, 64);
            int   oi = __shfl_xor(ix, m, 64);
            float o2 = __shfl_xor(v2, m, 64);
            if (o1 < v1 || (o1 == v1 && oi < ix)) { v2 = fminf(v1, o2); v1 = o1; ix = oi; }
            else v2 = fminf(v2, o1);
        }
        b1[sl] = v1; b2[sl] = v2; i1[sl] = ix;
    }
    if (l15 == 0) {
        #pragma unroll
        for (int mi = 0; mi < 4; ++mi)
            #pragma unroll
            for (int r = 0; r < 4; ++r) {
                int rl = mi * 16 + g4 * 4 + r;
                m_b1[w][rl] = b1[mi * 4 + r];
                m_b2[w][rl] = b2[mi * 4 + r];
                m_i1[w][rl] = i1[mi * 4 + r];
            }
    }
    __syncthreads();
    if (tid < 64) {
        float v1 = m_b1[0][tid], v2 = m_b2[0][tid]; int ix = m_i1[0][tid];
        #pragma unroll
        for (int wv = 1; wv < 4; ++wv) {
            float o1 = m_b1[wv][tid], o2 = m_b2[wv][tid]; int oi = m_i1[wv][tid];
            if (o1 < v1 || (o1 == v1 && oi < ix)) { v2 = fminf(v1, o2); v1 = o1; ix = oi; }
            else v2 = fminf(v2, o1);
        }
        idx_out[m0 + tid] = (float)ix;
        if (v2 - v1 <= TAU) { int p = atomicAdd(count, 1); flags[p] = m0 + tid; }
    }
}

// ---------- exact fp32 rescore of flagged rows (r1 arithmetic) ----------
__global__ void rescore_kernel(const float* __restrict__ in, const float* __restrict__ cb,
                               const float* __restrict__ bn, const float* __restrict__ xn,
                               const int* __restrict__ flags, const int* __restrict__ count,
                               float* __restrict__ idx_out) {
    __shared__ float xrow[128];
    __shared__ float sv[256];
    __shared__ int kv[256];
    const int tid = threadIdx.x;
    const int cnt = count[0];
    for (int f = blockIdx.x; f < cnt; f += gridDim.x) {
        const int row = flags[f];
        if (tid < 128) {
            int b = row >> 14;
            xrow[tid] = in[b * 2097152 + tid * 16384 + (row & 16383)];
        }
        __syncthreads();
        const float xnv = xn[row];
        float best = 3.4e38f; int bi = 0;
        const int t4 = tid * 4;
        for (int k = t4; k < t4 + 4; ++k) {
            const float4* cr = reinterpret_cast<const float4*>(cb + (size_t)k * 128);
            float dot = 0.f;
            #pragma unroll
            for (int c4 = 0; c4 < 32; ++c4) {
                float4 bv = cr[c4];
                float4 xv = *reinterpret_cast<const float4*>(&xrow[c4 * 4]);
                dot = fmaf(xv.x, bv.x, dot); dot = fmaf(xv.y, bv.y, dot);
                dot = fmaf(xv.z, bv.z, dot); dot = fmaf(xv.w, bv.w, dot);
            }
            float t1 = xnv + bn[k];
            float s = fmaf(-2.0f, dot, t1);
            if (s < best) { best = s; bi = k; }
        }
        sv[tid] = best; kv[tid] = bi;
        __syncthreads();
        for (int off = 128; off > 0; off >>= 1) {
            if (tid < off) {
                if (sv[tid + off] < sv[tid] ||
                    (sv[tid + off] == sv[tid] && kv[tid + off] < kv[tid])) {
                    sv[tid] = sv[tid + off]; kv[tid] = kv[tid + off];
                }
            }
            __syncthreads();
        }
        if (tid == 0) idx_out[row] = (float)kv[0];
        __syncthreads();
    }
}

// ---------- quantize + straight-through + loss partials (r1 epilogue) ----------
__global__ void quantize_kernel(const float* __restrict__ in, const float* __restrict__ cb,
                                const float* __restrict__ idxf, float* __restrict__ out_q,
                                float* __restrict__ partials) {
    __shared__ int idx_s[64];
    __shared__ float red_s[4];
    const int tid = threadIdx.x;
    const int n0 = blockIdx.x * 64;
    if (tid < 64) idx_s[tid] = (int)idxf[n0 + tid];
    __syncthreads();
    float acc = 0.f;
    const float4* cb4 = reinterpret_cast<const float4*>(cb);
    const float4* in4 = reinterpret_cast<const float4*>(in);
    float4* out4 = reinterpret_cast<float4*>(out_q);
    #pragma unroll
    for (int i = 0; i < 8; ++i) {
        int idx = tid + i * 256;
        int row = idx >> 5;
        int c4 = idx & 31;
        int kq = idx_s[row];
        float4 q = cb4[kq * 32 + c4];
        float4 x = in4[(size_t)(n0 + row) * 32 + c4];
        float4 d, o;
        d.x = q.x - x.x; d.y = q.y - x.y; d.z = q.z - x.z; d.w = q.w - x.w;
        o.x = x.x + d.x; o.y = x.y + d.y; o.z = x.z + d.z; o.w = x.w + d.w;
        out4[(size_t)(n0 + row) * 32 + c4] = o;
        acc += d.x * d.x; acc += d.y * d.y; acc += d.z * d.z; acc += d.w * d.w;
    }
    #pragma unroll
    for (int m = 1; m < 64; m <<= 1) acc += __shfl_xor(acc, m, 64);
    if ((tid & 63) == 0) red_s[tid >> 6] = acc;
    __syncthreads();
    if (tid == 0) partials[blockIdx.x] = red_s[0] + red_s[1] + red_s[2] + red_s[3];
}

__global__ void loss_final_kernel(const float* __restrict__ partials, float* __restrict__ out_loss) {
    __shared__ float red_s[4];
    float s = 0.f;
    for (int i = threadIdx.x; i < 2048; i += 256) s += partials[i];
    #pragma unroll
    for (int m = 1; m < 64; m <<= 1) s += __shfl_xor(s, m, 64);
    if ((threadIdx.x & 63) == 0) red_s[threadIdx.x >> 6] = s;
    __syncthreads();
    if (threadIdx.x == 0) {
        float tot = red_s[0] + red_s[1] + red_s[2] + red_s[3];
        out_loss[0] = 1.25f * (tot / (float)NUMEL);
    }
}

extern "C" void kernel_launch(void* const* d_in, const int* in_sizes, int n_in,
                              void* d_out, int out_size, void* d_ws, size_t ws_size,
                              hipStream_t stream) {
    (void)in_sizes; (void)n_in; (void)out_size; (void)ws_size;
    const float* in = (const float*)d_in[0];
    const float* cb = (const float*)d_in[1];
    float* out = (float*)d_out;

    char* ws = (char*)d_ws;
    float*    bn       = (float*)(ws + 0);
    float*    xn       = (float*)(ws + 4096);
    ushort_t* Bpl      = (ushort_t*)(ws + 528384);
    int*      flags    = (int*)(ws + 1052672);
    int*      count    = (int*)(ws + 1576960);
    float*    partials = (float*)(ws + 1577088);

    // A hi/lo planes live in the (not yet written) quantized-output region:
    // exactly NUMEL*4 bytes = N_ROWS*256 bf16.
    ushort_t* Apl = (ushort_t*)d_out;
    float* idxf = out + NUMEL + 1;

    prep_cb_kernel<<<4, 256, 0, stream>>>(cb, bn, Bpl, count);
    prep_x_kernel<<<2048, 256, 0, stream>>>(in, xn, Apl);
    gemm_argmin_kernel<<<2048, 256, 0, stream>>>(Apl, Bpl, bn, xn, idxf, flags, count);
    rescore_kernel<<<512, 256, 0, stream>>>(in, cb, bn, xn, flags, count, idxf);
    quantize_kernel<<<2048, 256, 0, stream>>>(in, cb, idxf, out, partials);
    loss_final_kernel<<<1, 256, 0, stream>>>(partials, out + NUMEL);
}

// Round 3
// 690.227 us; speedup vs baseline: 1.3123x; 1.3123x over previous
//
#include <hip/hip_runtime.h>

typedef unsigned short u16;
typedef __attribute__((ext_vector_type(8))) short bf16x8;
typedef __attribute__((ext_vector_type(4))) float f32x4;

#define K_CB  1024
#define N_ROWS 131072
#define NUMEL (N_ROWS * 128)
#define TAU 1.5e-4f

#define GLOAD16(gp, lp) __builtin_amdgcn_global_load_lds( \
    (const __attribute__((address_space(1))) unsigned int*)(gp), \
    (__attribute__((address_space(3))) unsigned int*)(lp), 16, 0, 0)

__device__ __forceinline__ u16 f2bf(float x) {
    union { float f; unsigned int u; } a; a.f = x;
    unsigned int r = a.u + 0x7fffu + ((a.u >> 16) & 1u);
    return (u16)(r >> 16);
}
__device__ __forceinline__ float bf2f(u16 h) {
    union { unsigned int u; float f; } a; a.u = ((unsigned int)h) << 16;
    return a.f;
}

// ---------- prep codebook: bn + slice-major bf16 hi/lo planes ----------
// Bpl layout: [32 slices][1024 rows][8 bf16]; slice s<16: hi of ch [8s,8s+8),
// s>=16: lo of ch [8(s-16), ...).
__global__ void prep_cb_kernel(const float* __restrict__ cb, float* __restrict__ bn,
                               u16* __restrict__ Bpl, int* __restrict__ count) {
    int k = blockIdx.x * 256 + threadIdx.x;
    if (blockIdx.x == 0 && threadIdx.x == 0) count[0] = 0;
    if (k >= K_CB) return;
    const float4* row4 = reinterpret_cast<const float4*>(cb) + k * 32;
    float s = 0.f;
    #pragma unroll
    for (int i = 0; i < 32; ++i) {
        float4 v = row4[i];
        s = fmaf(v.x, v.x, s); s = fmaf(v.y, v.y, s);
        s = fmaf(v.z, v.z, s); s = fmaf(v.w, v.w, s);
    }
    bn[k] = s;
    const float* rf = cb + k * 128;
    #pragma unroll
    for (int s8 = 0; s8 < 16; ++s8) {
        uint4 H, L;
        unsigned int hw[8], lw[8];
        #pragma unroll
        for (int j = 0; j < 8; ++j) {
            float x = rf[s8 * 8 + j];
            u16 h = f2bf(x);
            hw[j] = h;
            lw[j] = f2bf(x - bf2f(h));
        }
        H.x = hw[0] | (hw[1] << 16); H.y = hw[2] | (hw[3] << 16);
        H.z = hw[4] | (hw[5] << 16); H.w = hw[6] | (hw[7] << 16);
        L.x = lw[0] | (lw[1] << 16); L.y = lw[2] | (lw[3] << 16);
        L.z = lw[4] | (lw[5] << 16); L.w = lw[6] | (lw[7] << 16);
        *reinterpret_cast<uint4*>(&Bpl[((size_t)s8 * 1024 + k) * 8]) = H;
        *reinterpret_cast<uint4*>(&Bpl[((size_t)(16 + s8) * 1024 + k) * 8]) = L;
    }
}

// ---------- fused: transpose + planes + MFMA GEMM + argmin + quantize + loss ----------
__launch_bounds__(256, 2)
__global__ void gemm_fused_kernel(const float* __restrict__ in, const float* __restrict__ cb,
                                  const u16* __restrict__ Bpl, const float* __restrict__ bn,
                                  float* __restrict__ out_q, float* __restrict__ idx_out,
                                  int* __restrict__ flags, int* __restrict__ count,
                                  float* __restrict__ deltas, float* __restrict__ partials) {
    __shared__ float xs[64 * 132];            // 33792 B; reused as A planes (32768 B)
    __shared__ u16 Bb[2 * 4 * 256 * 8];       // 32768 B
    __shared__ float bn_s[K_CB];              // 4096 B
    __shared__ float m_b1[4][64];
    __shared__ float m_b2[4][64];
    __shared__ int   m_i1[4][64];
    __shared__ int   idx_s[64];
    __shared__ float red_s[4];

    const int tid = threadIdx.x;
    const int w = tid >> 6, lane = tid & 63, g4 = lane >> 4, l15 = lane & 15;
    const int blk = blockIdx.x, n0 = blk * 64;
    u16* A = (u16*)xs;

    // issue B prologue early (chunk 0, cc=0 -> hi slices 0..3, rows 0..255)
    #pragma unroll
    for (int i = 0; i < 4; ++i) {
        const u16* g = Bpl + (size_t)(w * 1024 + i * 64 + lane) * 8;
        GLOAD16(g, &Bb[((0 * 4 + w) * 256 + i * 64) * 8]);
    }

    // stage x tile: [B,C,D,H,W] -> xs[n][c]
    {
        const int base = (n0 >> 14) * (128 * 16384) + (n0 & 16383);
        #pragma unroll
        for (int i = 0; i < 8; ++i) {
            int idx = tid + i * 256;
            int nl = idx & 63, c4 = idx >> 6;
            float4 v;
            v.x = in[base + (c4 * 4 + 0) * 16384 + nl];
            v.y = in[base + (c4 * 4 + 1) * 16384 + nl];
            v.z = in[base + (c4 * 4 + 2) * 16384 + nl];
            v.w = in[base + (c4 * 4 + 3) * 16384 + nl];
            *reinterpret_cast<float4*>(&xs[nl * 132 + c4 * 4]) = v;
        }
    }
    for (int i = tid; i < K_CB; i += 256) bn_s[i] = bn[i];
    __syncthreads();

    // build A fragments in registers (slice-major), then overwrite xs region
    uint4 afr[8];
    const int arow = tid & 63, sg = tid >> 6;
    #pragma unroll
    for (int i = 0; i < 8; ++i) {
        int s = sg * 8 + i;           // 0..31
        int plane = s >> 4;
        int ch0 = (s & 15) * 8;
        float4 va = *reinterpret_cast<const float4*>(&xs[arow * 132 + ch0]);
        float4 vb = *reinterpret_cast<const float4*>(&xs[arow * 132 + ch0 + 4]);
        float v[8] = {va.x, va.y, va.z, va.w, vb.x, vb.y, vb.z, vb.w};
        unsigned int pw[8];
        #pragma unroll
        for (int j = 0; j < 8; ++j) {
            u16 h = f2bf(v[j]);
            pw[j] = plane ? (unsigned int)f2bf(v[j] - bf2f(h)) : (unsigned int)h;
        }
        afr[i].x = pw[0] | (pw[1] << 16); afr[i].y = pw[2] | (pw[3] << 16);
        afr[i].z = pw[4] | (pw[5] << 16); afr[i].w = pw[6] | (pw[7] << 16);
    }
    __syncthreads();   // all xs reads done
    #pragma unroll
    for (int i = 0; i < 8; ++i) {
        int s = sg * 8 + i;
        *reinterpret_cast<uint4*>(&A[(s * 64 + arow) * 8]) = afr[i];
    }
    __syncthreads();   // A ready; prologue gloads drained

    f32x4 acc[4][4];
    const f32x4 zz = {0.f, 0.f, 0.f, 0.f};
    #pragma unroll
    for (int mi = 0; mi < 4; ++mi)
        #pragma unroll
        for (int ni = 0; ni < 4; ++ni) acc[mi][ni] = zz;

    float b1[16], b2[16]; int i1[16];
    #pragma unroll
    for (int sl = 0; sl < 16; ++sl) { b1[sl] = 3.4e38f; b2[sl] = 3.4e38f; i1[sl] = 0; }

    // 48 k-slice iterations: 4 cb-chunks x 12 plane-slices
    // cc 0..3: hiA*hiB, 4..7: hiA*loB, 8..11: loA*hiB (ks = cc&3)
    for (int t = 0; t < 48; ++t) {
        const int chunk = t / 12, cc = t % 12, buf = t & 1;
        if (t < 47) {
            const int t2 = t + 1, chunk2 = t2 / 12, cc2 = t2 % 12, nb = t2 & 1;
            const int bs = ((cc2 >= 4 && cc2 < 8) ? 16 : 0) + (cc2 & 3) * 4;
            const int cb0 = chunk2 * 256;
            #pragma unroll
            for (int i = 0; i < 4; ++i) {
                const u16* g = Bpl + (size_t)((bs + w) * 1024 + cb0 + i * 64 + lane) * 8;
                GLOAD16(g, &Bb[((nb * 4 + w) * 256 + i * 64) * 8]);
            }
        }
        const int aoff = ((cc >= 8) ? 16 : 0) + (cc & 3) * 4;

        bf16x8 af[4], bfr[4];
        #pragma unroll
        for (int mi = 0; mi < 4; ++mi)
            af[mi] = *reinterpret_cast<const bf16x8*>(&A[((aoff + g4) * 64 + mi * 16 + l15) * 8]);
        #pragma unroll
        for (int ni = 0; ni < 4; ++ni)
            bfr[ni] = *reinterpret_cast<const bf16x8*>(
                &Bb[((buf * 4 + g4) * 256 + w * 64 + ni * 16 + l15) * 8]);
        #pragma unroll
        for (int mi = 0; mi < 4; ++mi)
            #pragma unroll
            for (int ni = 0; ni < 4; ++ni)
                acc[mi][ni] = __builtin_amdgcn_mfma_f32_16x16x32_bf16(af[mi], bfr[ni], acc[mi][ni], 0, 0, 0);

        if (cc == 11) {
            const int cb0s = chunk * 256;
            #pragma unroll
            for (int mi = 0; mi < 4; ++mi) {
                #pragma unroll
                for (int ni = 0; ni < 4; ++ni) {
                    int n = cb0s + w * 64 + ni * 16 + l15;
                    float bnv = bn_s[n];
                    #pragma unroll
                    for (int r = 0; r < 4; ++r) {
                        float s = fmaf(-2.0f, acc[mi][ni][r], bnv);
                        int sl = mi * 4 + r;
                        if (s < b1[sl]) { b2[sl] = b1[sl]; b1[sl] = s; i1[sl] = n; }
                        else if (s < b2[sl]) b2[sl] = s;
                    }
                    acc[mi][ni] = zz;
                }
            }
        }
        __syncthreads();
    }

    // argmin merge: across 16 l15 lanes
    #pragma unroll
    for (int sl = 0; sl < 16; ++sl) {
        float v1 = b1[sl], v2 = b2[sl]; int ix = i1[sl];
        #pragma unroll
        for (int m = 1; m < 16; m <<= 1) {
            float o1 = __shfl_xor(v1, m, 64);
            int   oi = __shfl_xor(ix, m, 64);
            float o2 = __shfl_xor(v2, m, 64);
            if (o1 < v1 || (o1 == v1 && oi < ix)) { v2 = fminf(v1, o2); v1 = o1; ix = oi; }
            else v2 = fminf(v2, o1);
        }
        b1[sl] = v1; b2[sl] = v2; i1[sl] = ix;
    }
    if (l15 == 0) {
        #pragma unroll
        for (int mi = 0; mi < 4; ++mi)
            #pragma unroll
            for (int r = 0; r < 4; ++r) {
                int rl = mi * 16 + g4 * 4 + r;
                m_b1[w][rl] = b1[mi * 4 + r];
                m_b2[w][rl] = b2[mi * 4 + r];
                m_i1[w][rl] = i1[mi * 4 + r];
            }
    }
    __syncthreads();
    if (tid < 64) {
        float v1 = m_b1[0][tid], v2 = m_b2[0][tid]; int ix = m_i1[0][tid];
        #pragma unroll
        for (int wv = 1; wv < 4; ++wv) {
            float o1 = m_b1[wv][tid], o2 = m_b2[wv][tid]; int oi = m_i1[wv][tid];
            if (o1 < v1 || (o1 == v1 && oi < ix)) { v2 = fminf(v1, o2); v1 = o1; ix = oi; }
            else v2 = fminf(v2, o1);
        }
        idx_s[tid] = ix;
        idx_out[n0 + tid] = (float)ix;
        deltas[n0 + tid] = 0.f;
        if (v2 - v1 <= TAU) { int p = atomicAdd(count, 1); flags[p] = n0 + tid; }
    }
    __syncthreads();

    // fused quantize + straight-through + loss partial (linear flat layout)
    float acc_l = 0.f;
    const float4* cb4 = reinterpret_cast<const float4*>(cb);
    const float4* in4 = reinterpret_cast<const float4*>(in);
    float4* out4 = reinterpret_cast<float4*>(out_q);
    #pragma unroll
    for (int i = 0; i < 8; ++i) {
        int idx = tid + i * 256;
        int row = idx >> 5;
        int c4 = idx & 31;
        int kq = idx_s[row];
        float4 q = cb4[kq * 32 + c4];
        float4 x = in4[(size_t)(n0 + row) * 32 + c4];
        float4 d, o;
        d.x = q.x - x.x; d.y = q.y - x.y; d.z = q.z - x.z; d.w = q.w - x.w;
        o.x = x.x + d.x; o.y = x.y + d.y; o.z = x.z + d.z; o.w = x.w + d.w;
        out4[(size_t)(n0 + row) * 32 + c4] = o;
        acc_l += d.x * d.x; acc_l += d.y * d.y; acc_l += d.z * d.z; acc_l += d.w * d.w;
    }
    #pragma unroll
    for (int m = 1; m < 64; m <<= 1) acc_l += __shfl_xor(acc_l, m, 64);
    if ((tid & 63) == 0) red_s[tid >> 6] = acc_l;
    __syncthreads();
    if (tid == 0) partials[blk] = red_s[0] + red_s[1] + red_s[2] + red_s[3];
}

// ---------- exact fp32 rescore + output/loss patch for flagged rows ----------
__global__ void rescore_kernel(const float* __restrict__ in, const float* __restrict__ cb,
                               const float* __restrict__ bn, const int* __restrict__ flags,
                               const int* __restrict__ count, float* __restrict__ idx_out,
                               float* __restrict__ out_q, float* __restrict__ deltas) {
    __shared__ float xrow[128];
    __shared__ float sv[256];
    __shared__ int kv[256];
    __shared__ float xn_sh;
    __shared__ float dred[32];
    const int tid = threadIdx.x;
    const int cnt = count[0];
    const float4* cb4 = reinterpret_cast<const float4*>(cb);
    const float4* in4 = reinterpret_cast<const float4*>(in);
    float4* out4 = reinterpret_cast<float4*>(out_q);
    for (int f = blockIdx.x; f < cnt; f += gridDim.x) {
        const int row = flags[f];
        if (tid < 128) {
            int b = row >> 14;
            xrow[tid] = in[b * 2097152 + tid * 16384 + (row & 16383)];
        }
        __syncthreads();
        if (tid == 0) {
            float s = 0.f;
            for (int c = 0; c < 128; ++c) s = fmaf(xrow[c], xrow[c], s);
            xn_sh = s;
        }
        __syncthreads();
        const float xnv = xn_sh;
        float best = 3.4e38f; int bi = 0;
        const int t4 = tid * 4;
        for (int k = t4; k < t4 + 4; ++k) {
            const float4* cr = cb4 + (size_t)k * 32;
            float dot = 0.f;
            #pragma unroll
            for (int c4 = 0; c4 < 32; ++c4) {
                float4 bv = cr[c4];
                float4 xv = *reinterpret_cast<const float4*>(&xrow[c4 * 4]);
                dot = fmaf(xv.x, bv.x, dot); dot = fmaf(xv.y, bv.y, dot);
                dot = fmaf(xv.z, bv.z, dot); dot = fmaf(xv.w, bv.w, dot);
            }
            float t1 = xnv + bn[k];
            float s = fmaf(-2.0f, dot, t1);
            if (s < best) { best = s; bi = k; }
        }
        sv[tid] = best; kv[tid] = bi;
        __syncthreads();
        for (int off = 128; off > 0; off >>= 1) {
            if (tid < off) {
                if (sv[tid + off] < sv[tid] ||
                    (sv[tid + off] == sv[tid] && kv[tid + off] < kv[tid])) {
                    sv[tid] = sv[tid + off]; kv[tid] = kv[tid + off];
                }
            }
            __syncthreads();
        }
        const int k_new = kv[0];
        const int k_old = (int)idx_out[row];
        if (k_new != k_old) {
            if (tid == 0) idx_out[row] = (float)k_new;
            if (tid < 32) {
                float4 x = in4[(size_t)row * 32 + tid];
                float4 qn = cb4[(size_t)k_new * 32 + tid];
                float4 qo = cb4[(size_t)k_old * 32 + tid];
                float4 dn, dl, o;
                dn.x = qn.x - x.x; dn.y = qn.y - x.y; dn.z = qn.z - x.z; dn.w = qn.w - x.w;
                o.x = x.x + dn.x; o.y = x.y + dn.y; o.z = x.z + dn.z; o.w = x.w + dn.w;
                out4[(size_t)row * 32 + tid] = o;
                dl.x = qo.x - x.x; dl.y = qo.y - x.y; dl.z = qo.z - x.z; dl.w = qo.w - x.w;
                float dd = dn.x * dn.x + dn.y * dn.y + dn.z * dn.z + dn.w * dn.w
                         - (dl.x * dl.x + dl.y * dl.y + dl.z * dl.z + dl.w * dl.w);
                dred[tid] = dd;
            }
            __syncthreads();
            if (tid == 0) {
                float s = 0.f;
                for (int i = 0; i < 32; ++i) s += dred[i];
                deltas[row] = s;
            }
        }
        __syncthreads();
    }
}

// ---------- deterministic 2-stage loss reduce ----------
__global__ void loss_stage1(const float* __restrict__ partials, const float* __restrict__ deltas,
                            float* __restrict__ part2) {
    __shared__ float red_s[4];
    const int blk = blockIdx.x, tid = threadIdx.x;
    float s = 0.f;
    const float* dp = deltas + blk * 2048;
    for (int i = tid; i < 2048; i += 256) s += dp[i];
    if (tid < 32) s += partials[blk * 32 + tid];
    #pragma unroll
    for (int m = 1; m < 64; m <<= 1) s += __shfl_xor(s, m, 64);
    if ((tid & 63) == 0) red_s[tid >> 6] = s;
    __syncthreads();
    if (tid == 0) part2[blk] = red_s[0] + red_s[1] + red_s[2] + red_s[3];
}

__global__ void loss_stage2(const float* __restrict__ part2, float* __restrict__ out_loss) {
    const int tid = threadIdx.x;
    float s = part2[tid];
    #pragma unroll
    for (int m = 1; m < 64; m <<= 1) s += __shfl_xor(s, m, 64);
    if (tid == 0) out_loss[0] = 1.25f * (s / (float)NUMEL);
}

extern "C" void kernel_launch(void* const* d_in, const int* in_sizes, int n_in,
                              void* d_out, int out_size, void* d_ws, size_t ws_size,
                              hipStream_t stream) {
    (void)in_sizes; (void)n_in; (void)out_size; (void)ws_size;
    const float* in = (const float*)d_in[0];
    const float* cb = (const float*)d_in[1];
    float* out = (float*)d_out;

    char* ws = (char*)d_ws;
    float* bn       = (float*)(ws + 0);          //    4096 B
    u16*   Bpl      = (u16*)(ws + 4096);         //  524288 B
    int*   flags    = (int*)(ws + 528384);       //  524288 B
    float* deltas   = (float*)(ws + 1052672);    //  524288 B
    float* partials = (float*)(ws + 1576960);    //    8192 B
    float* part2    = (float*)(ws + 1585152);    //     256 B
    int*   count    = (int*)(ws + 1585408);      //     128 B

    float* idxf = out + NUMEL + 1;

    prep_cb_kernel<<<4, 256, 0, stream>>>(cb, bn, Bpl, count);
    gemm_fused_kernel<<<2048, 256, 0, stream>>>(in, cb, Bpl, bn, out, idxf,
                                                flags, count, deltas, partials);
    rescore_kernel<<<512, 256, 0, stream>>>(in, cb, bn, flags, count, idxf, out, deltas);
    loss_stage1<<<64, 256, 0, stream>>>(partials, deltas, part2);
    loss_stage2<<<1, 64, 0, stream>>>(part2, out + NUMEL);
}

// Round 4
// 375.627 us; speedup vs baseline: 2.4113x; 1.8375x over previous
//
#include <hip/hip_runtime.h>

typedef unsigned short u16;
typedef __attribute__((ext_vector_type(8))) short bf16x8;
typedef __attribute__((ext_vector_type(4))) float f32x4;

#define K_CB  1024
#define N_ROWS 131072
#define NUMEL (N_ROWS * 128)
#define TAU 1.5e-4f
#define SMALLCAP 32768
#define FULLCAP  32768

#define GLOAD16(gp, lp) __builtin_amdgcn_global_load_lds( \
    (const __attribute__((address_space(1))) unsigned int*)(gp), \
    (__attribute__((address_space(3))) unsigned int*)(lp), 16, 0, 0)

__device__ __forceinline__ u16 f2bf(float x) {
    union { float f; unsigned int u; } a; a.f = x;
    unsigned int r = a.u + 0x7fffu + ((a.u >> 16) & 1u);
    return (u16)(r >> 16);
}
__device__ __forceinline__ float bf2f(u16 h) {
    union { unsigned int u; float f; } a; a.u = ((unsigned int)h) << 16;
    return a.f;
}

// ---------- prep codebook: bn + slice-major bf16 hi/lo planes ----------
__global__ void prep_cb_kernel(const float* __restrict__ cb, float* __restrict__ bn,
                               u16* __restrict__ Bpl, int* __restrict__ cnts) {
    int k = blockIdx.x * 256 + threadIdx.x;
    if (blockIdx.x == 0 && threadIdx.x < 2) cnts[threadIdx.x] = 0;
    if (k >= K_CB) return;
    const float4* row4 = reinterpret_cast<const float4*>(cb) + k * 32;
    float s = 0.f;
    #pragma unroll
    for (int i = 0; i < 32; ++i) {
        float4 v = row4[i];
        s = fmaf(v.x, v.x, s); s = fmaf(v.y, v.y, s);
        s = fmaf(v.z, v.z, s); s = fmaf(v.w, v.w, s);
    }
    bn[k] = s;
    const float* rf = cb + k * 128;
    #pragma unroll
    for (int s8 = 0; s8 < 16; ++s8) {
        uint4 H, L;
        unsigned int hw[8], lw[8];
        #pragma unroll
        for (int j = 0; j < 8; ++j) {
            float x = rf[s8 * 8 + j];
            u16 h = f2bf(x);
            hw[j] = h;
            lw[j] = f2bf(x - bf2f(h));
        }
        H.x = hw[0] | (hw[1] << 16); H.y = hw[2] | (hw[3] << 16);
        H.z = hw[4] | (hw[5] << 16); H.w = hw[6] | (hw[7] << 16);
        L.x = lw[0] | (lw[1] << 16); L.y = lw[2] | (lw[3] << 16);
        L.z = lw[4] | (lw[5] << 16); L.w = lw[6] | (lw[7] << 16);
        *reinterpret_cast<uint4*>(&Bpl[((size_t)s8 * 1024 + k) * 8]) = H;
        *reinterpret_cast<uint4*>(&Bpl[((size_t)(16 + s8) * 1024 + k) * 8]) = L;
    }
}

// ---------- fused: transpose + planes + MFMA GEMM + argmin + candidates + quantize + loss ----------
__launch_bounds__(256, 2)
__global__ void gemm_fused_kernel(const float* __restrict__ in, const float* __restrict__ cb,
                                  const u16* __restrict__ Bpl, const float* __restrict__ bn,
                                  float* __restrict__ out_q, float* __restrict__ idx_out,
                                  uint2* __restrict__ smallL, int* __restrict__ fullL,
                                  int* __restrict__ cnts,
                                  float* __restrict__ deltas, float* __restrict__ partials) {
    __shared__ float xs[64 * 132];            // 33792 B; reused as A planes
    __shared__ u16 Bb[2 * 4 * 256 * 8];       // 32768 B
    __shared__ float bn_s[K_CB];              // 4096 B
    __shared__ float m_b1[4][64];
    __shared__ float m_b2[4][64];
    __shared__ int   m_i1[4][64];
    __shared__ int   idx_s[64];
    __shared__ float gmin_s[64];
    __shared__ int   flg_s[64];
    __shared__ int   ccnt_s[64];
    __shared__ int   fb_s[64];
    __shared__ int   cand_s[64][4];
    __shared__ float red_s[4];

    const int tid = threadIdx.x;
    const int w = tid >> 6, lane = tid & 63, g4 = lane >> 4, l15 = lane & 15;
    const int blk = blockIdx.x, n0 = blk * 64;
    u16* A = (u16*)xs;

    // issue B prologue early
    #pragma unroll
    for (int i = 0; i < 4; ++i) {
        const u16* g = Bpl + (size_t)(w * 1024 + i * 64 + lane) * 8;
        GLOAD16(g, &Bb[((0 * 4 + w) * 256 + i * 64) * 8]);
    }

    // stage x tile
    {
        const int base = (n0 >> 14) * (128 * 16384) + (n0 & 16383);
        #pragma unroll
        for (int i = 0; i < 8; ++i) {
            int idx = tid + i * 256;
            int nl = idx & 63, c4 = idx >> 6;
            float4 v;
            v.x = in[base + (c4 * 4 + 0) * 16384 + nl];
            v.y = in[base + (c4 * 4 + 1) * 16384 + nl];
            v.z = in[base + (c4 * 4 + 2) * 16384 + nl];
            v.w = in[base + (c4 * 4 + 3) * 16384 + nl];
            *reinterpret_cast<float4*>(&xs[nl * 132 + c4 * 4]) = v;
        }
    }
    for (int i = tid; i < K_CB; i += 256) bn_s[i] = bn[i];
    __syncthreads();

    // build A fragments in registers (slice-major), then overwrite xs region
    uint4 afr[8];
    const int arow = tid & 63, sg = tid >> 6;
    #pragma unroll
    for (int i = 0; i < 8; ++i) {
        int s = sg * 8 + i;
        int plane = s >> 4;
        int ch0 = (s & 15) * 8;
        float4 va = *reinterpret_cast<const float4*>(&xs[arow * 132 + ch0]);
        float4 vb = *reinterpret_cast<const float4*>(&xs[arow * 132 + ch0 + 4]);
        float v[8] = {va.x, va.y, va.z, va.w, vb.x, vb.y, vb.z, vb.w};
        unsigned int pw[8];
        #pragma unroll
        for (int j = 0; j < 8; ++j) {
            u16 h = f2bf(v[j]);
            pw[j] = plane ? (unsigned int)f2bf(v[j] - bf2f(h)) : (unsigned int)h;
        }
        afr[i].x = pw[0] | (pw[1] << 16); afr[i].y = pw[2] | (pw[3] << 16);
        afr[i].z = pw[4] | (pw[5] << 16); afr[i].w = pw[6] | (pw[7] << 16);
    }
    __syncthreads();
    #pragma unroll
    for (int i = 0; i < 8; ++i) {
        int s = sg * 8 + i;
        *reinterpret_cast<uint4*>(&A[(s * 64 + arow) * 8]) = afr[i];
    }
    __syncthreads();

    f32x4 acc[4][4];
    const f32x4 zz = {0.f, 0.f, 0.f, 0.f};
    #pragma unroll
    for (int mi = 0; mi < 4; ++mi)
        #pragma unroll
        for (int ni = 0; ni < 4; ++ni) acc[mi][ni] = zz;

    float b1[16], b2[16]; int i1[16];
    #pragma unroll
    for (int sl = 0; sl < 16; ++sl) { b1[sl] = 3.4e38f; b2[sl] = 3.4e38f; i1[sl] = 0; }

    for (int t = 0; t < 48; ++t) {
        const int chunk = t / 12, cc = t % 12, buf = t & 1;
        if (t < 47) {
            const int t2 = t + 1, chunk2 = t2 / 12, cc2 = t2 % 12, nb = t2 & 1;
            const int bs = ((cc2 >= 4 && cc2 < 8) ? 16 : 0) + (cc2 & 3) * 4;
            const int cb0 = chunk2 * 256;
            #pragma unroll
            for (int i = 0; i < 4; ++i) {
                const u16* g = Bpl + (size_t)((bs + w) * 1024 + cb0 + i * 64 + lane) * 8;
                GLOAD16(g, &Bb[((nb * 4 + w) * 256 + i * 64) * 8]);
            }
        }
        const int aoff = ((cc >= 8) ? 16 : 0) + (cc & 3) * 4;

        bf16x8 af[4], bfr[4];
        #pragma unroll
        for (int mi = 0; mi < 4; ++mi)
            af[mi] = *reinterpret_cast<const bf16x8*>(&A[((aoff + g4) * 64 + mi * 16 + l15) * 8]);
        #pragma unroll
        for (int ni = 0; ni < 4; ++ni)
            bfr[ni] = *reinterpret_cast<const bf16x8*>(
                &Bb[((buf * 4 + g4) * 256 + w * 64 + ni * 16 + l15) * 8]);
        #pragma unroll
        for (int mi = 0; mi < 4; ++mi)
            #pragma unroll
            for (int ni = 0; ni < 4; ++ni)
                acc[mi][ni] = __builtin_amdgcn_mfma_f32_16x16x32_bf16(af[mi], bfr[ni], acc[mi][ni], 0, 0, 0);

        if (cc == 11) {
            const int cb0s = chunk * 256;
            #pragma unroll
            for (int mi = 0; mi < 4; ++mi) {
                #pragma unroll
                for (int ni = 0; ni < 4; ++ni) {
                    int n = cb0s + w * 64 + ni * 16 + l15;
                    float bnv = bn_s[n];
                    #pragma unroll
                    for (int r = 0; r < 4; ++r) {
                        float s = fmaf(-2.0f, acc[mi][ni][r], bnv);
                        int sl = mi * 4 + r;
                        if (s < b1[sl]) { b2[sl] = b1[sl]; b1[sl] = s; i1[sl] = n; }
                        else if (s < b2[sl]) b2[sl] = s;
                    }
                    acc[mi][ni] = zz;
                }
            }
        }
        __syncthreads();
    }

    // merge across 16 l15 lanes (keep per-lane b1/b2/i1 intact for emission)
    #pragma unroll
    for (int sl = 0; sl < 16; ++sl) {
        float v1 = b1[sl], v2 = b2[sl]; int ix = i1[sl];
        #pragma unroll
        for (int m = 1; m < 16; m <<= 1) {
            float o1 = __shfl_xor(v1, m, 64);
            int   oi = __shfl_xor(ix, m, 64);
            float o2 = __shfl_xor(v2, m, 64);
            if (o1 < v1 || (o1 == v1 && oi < ix)) { v2 = fminf(v1, o2); v1 = o1; ix = oi; }
            else v2 = fminf(v2, o1);
        }
        if (l15 == 0) {
            int mi = sl >> 2, r = sl & 3;
            int rl = mi * 16 + g4 * 4 + r;
            m_b1[w][rl] = v1; m_b2[w][rl] = v2; m_i1[w][rl] = ix;
        }
    }
    __syncthreads();
    if (tid < 64) {
        float v1 = m_b1[0][tid], v2 = m_b2[0][tid]; int ix = m_i1[0][tid];
        #pragma unroll
        for (int wv = 1; wv < 4; ++wv) {
            float o1 = m_b1[wv][tid], o2 = m_b2[wv][tid]; int oi = m_i1[wv][tid];
            if (o1 < v1 || (o1 == v1 && oi < ix)) { v2 = fminf(v1, o2); v1 = o1; ix = oi; }
            else v2 = fminf(v2, o1);
        }
        idx_s[tid] = ix;
        idx_out[n0 + tid] = (float)ix;
        deltas[n0 + tid] = 0.f;
        gmin_s[tid] = v1;
        flg_s[tid] = (v2 - v1 <= TAU) ? 1 : 0;
        ccnt_s[tid] = 0;
        fb_s[tid] = 0;
    }
    __syncthreads();

    // candidate emission: each (w,l15) bucket offers its best if within TAU of row min
    #pragma unroll
    for (int sl = 0; sl < 16; ++sl) {
        int mi = sl >> 2, r = sl & 3;
        int rl = mi * 16 + g4 * 4 + r;
        if (flg_s[rl]) {
            float g = gmin_s[rl];
            if (b1[sl] - g <= TAU) {
                int p = atomicAdd(&ccnt_s[rl], 1);
                if (p < 4) cand_s[rl][p] = i1[sl]; else fb_s[rl] = 1;
            }
            if (b2[sl] - g <= TAU) fb_s[rl] = 1;  // can't bound 3rd-in-bucket
        }
    }
    __syncthreads();
    if (tid < 64 && flg_s[tid]) {
        int nc = ccnt_s[tid];
        int row = n0 + tid;
        if (!fb_s[tid] && nc >= 2) {        // nc<=4 guaranteed when !fb
            int p = atomicAdd(&cnts[0], 1);
            if (p < SMALLCAP) {
                unsigned long long key = (unsigned long long)row |
                                         ((unsigned long long)nc << 20);
                for (int j = 0; j < nc; ++j)
                    key |= (unsigned long long)(cand_s[tid][j] & 1023) << (24 + 10 * j);
                uint2 rec; rec.x = (unsigned)key; rec.y = (unsigned)(key >> 32);
                smallL[p] = rec;
            } else {
                int q = atomicAdd(&cnts[1], 1);
                if (q < FULLCAP) fullL[q] = row;
            }
        } else if (fb_s[tid]) {
            int q = atomicAdd(&cnts[1], 1);
            if (q < FULLCAP) fullL[q] = row;
        }
        // nc<2 && !fb: approx winner is the only candidate in range -> keep
    }
    __syncthreads();

    // fused quantize + straight-through + loss partial
    float acc_l = 0.f;
    const float4* cb4 = reinterpret_cast<const float4*>(cb);
    const float4* in4 = reinterpret_cast<const float4*>(in);
    float4* out4 = reinterpret_cast<float4*>(out_q);
    #pragma unroll
    for (int i = 0; i < 8; ++i) {
        int idx = tid + i * 256;
        int row = idx >> 5;
        int c4 = idx & 31;
        int kq = idx_s[row];
        float4 q = cb4[kq * 32 + c4];
        float4 x = in4[(size_t)(n0 + row) * 32 + c4];
        float4 d, o;
        d.x = q.x - x.x; d.y = q.y - x.y; d.z = q.z - x.z; d.w = q.w - x.w;
        o.x = x.x + d.x; o.y = x.y + d.y; o.z = x.z + d.z; o.w = x.w + d.w;
        out4[(size_t)(n0 + row) * 32 + c4] = o;
        acc_l += d.x * d.x; acc_l += d.y * d.y; acc_l += d.z * d.z; acc_l += d.w * d.w;
    }
    #pragma unroll
    for (int m = 1; m < 64; m <<= 1) acc_l += __shfl_xor(acc_l, m, 64);
    if ((tid & 63) == 0) red_s[tid >> 6] = acc_l;
    __syncthreads();
    if (tid == 0) partials[blk] = red_s[0] + red_s[1] + red_s[2] + red_s[3];
}

// ---------- common patch helper (wave-level) ----------
__device__ __forceinline__ void patch_row(const float* __restrict__ in,
                                          const float* __restrict__ cb,
                                          float* __restrict__ idx_out,
                                          float* __restrict__ out_q,
                                          float* __restrict__ deltas,
                                          int row, int k_new, int lane) {
    int k_old = (int)idx_out[row];
    if (k_new == k_old) return;
    if (lane == 0) idx_out[row] = (float)k_new;
    float dd = 0.f;
    if (lane < 32) {
        const float4* in4 = reinterpret_cast<const float4*>(in);
        const float4* cb4 = reinterpret_cast<const float4*>(cb);
        float4* out4 = reinterpret_cast<float4*>(out_q);
        float4 x = in4[(size_t)row * 32 + lane];
        float4 qn = cb4[(size_t)k_new * 32 + lane];
        float4 qo = cb4[(size_t)k_old * 32 + lane];
        float4 dn, dl, o;
        dn.x = qn.x - x.x; dn.y = qn.y - x.y; dn.z = qn.z - x.z; dn.w = qn.w - x.w;
        o.x = x.x + dn.x; o.y = x.y + dn.y; o.z = x.z + dn.z; o.w = x.w + dn.w;
        out4[(size_t)row * 32 + lane] = o;
        dl.x = qo.x - x.x; dl.y = qo.y - x.y; dl.z = qo.z - x.z; dl.w = qo.w - x.w;
        dd = dn.x * dn.x + dn.y * dn.y + dn.z * dn.z + dn.w * dn.w
           - (dl.x * dl.x + dl.y * dl.y + dl.z * dl.z + dl.w * dl.w);
    }
    #pragma unroll
    for (int m = 1; m < 64; m <<= 1) dd += __shfl_xor(dd, m, 64);
    if (lane == 0) deltas[row] = dd;
}

// ---------- small rescore: one wave per record, <=4 candidates, exact arithmetic ----------
__global__ void small_rescore_kernel(const float* __restrict__ in, const float* __restrict__ cb,
                                     const float* __restrict__ bn, const uint2* __restrict__ recs,
                                     const int* __restrict__ cnts, float* __restrict__ idx_out,
                                     float* __restrict__ out_q, float* __restrict__ deltas) {
    __shared__ float xls[4][128];
    const int tid = threadIdx.x, wv = tid >> 6, lane = tid & 63;
    int ns = cnts[0]; if (ns > SMALLCAP) ns = SMALLCAP;
    float* xl = xls[wv];
    for (int f = blockIdx.x * 4 + wv; f < ns; f += gridDim.x * 4) {
        uint2 rc = recs[f];
        unsigned long long key = ((unsigned long long)rc.y << 32) | (unsigned long long)rc.x;
        int row = (int)(key & 131071ull);
        int nc = (int)((key >> 20) & 7ull);
        int ck = (lane < 4) ? (int)((key >> (24 + 10 * lane)) & 1023ull) : 0;
        // stage xrow
        const float* bp = in + (size_t)(row >> 14) * 2097152 + (row & 16383);
        xl[2 * lane]     = bp[(size_t)(2 * lane) * 16384];
        xl[2 * lane + 1] = bp[(size_t)(2 * lane + 1) * 16384];
        asm volatile("s_waitcnt vmcnt(0) lgkmcnt(0)" ::: "memory");
        // exact xn (serial fmaf, reference-order)
        float xn = 0.f;
        for (int c = 0; c < 128; ++c) { float v = xl[c]; xn = fmaf(v, v, xn); }
        float s = 3.4e38f; int kk = 0x7fffffff;
        if (lane < nc) {
            const float4* cr = reinterpret_cast<const float4*>(cb + (size_t)ck * 128);
            float dot = 0.f;
            #pragma unroll
            for (int c4 = 0; c4 < 32; ++c4) {
                float4 bv = cr[c4];
                float4 xv = *reinterpret_cast<const float4*>(&xl[c4 * 4]);
                dot = fmaf(xv.x, bv.x, dot); dot = fmaf(xv.y, bv.y, dot);
                dot = fmaf(xv.z, bv.z, dot); dot = fmaf(xv.w, bv.w, dot);
            }
            float t1 = xn + bn[ck];
            s = fmaf(-2.0f, dot, t1);
            kk = ck;
        }
        #pragma unroll
        for (int m = 1; m < 4; m <<= 1) {
            float os = __shfl_xor(s, m, 64);
            int ok = __shfl_xor(kk, m, 64);
            if (os < s || (os == s && ok < kk)) { s = os; kk = ok; }
        }
        int k_new = __shfl(kk, 0, 64);
        patch_row(in, cb, idx_out, out_q, deltas, row, k_new, lane);
    }
}

// ---------- full rescore fallback: one wave per row, exact arithmetic ----------
__global__ void full_rescore_kernel(const float* __restrict__ in, const float* __restrict__ cb,
                                    const float* __restrict__ bn, const int* __restrict__ fullL,
                                    const int* __restrict__ cnts, float* __restrict__ idx_out,
                                    float* __restrict__ out_q, float* __restrict__ deltas) {
    __shared__ float xls[4][128];
    const int tid = threadIdx.x, wv = tid >> 6, lane = tid & 63;
    int nf = cnts[1]; if (nf > FULLCAP) nf = FULLCAP;
    float* xl = xls[wv];
    for (int f = blockIdx.x * 4 + wv; f < nf; f += gridDim.x * 4) {
        int row = fullL[f];
        const float* bp = in + (size_t)(row >> 14) * 2097152 + (row & 16383);
        xl[2 * lane]     = bp[(size_t)(2 * lane) * 16384];
        xl[2 * lane + 1] = bp[(size_t)(2 * lane + 1) * 16384];
        asm volatile("s_waitcnt vmcnt(0) lgkmcnt(0)" ::: "memory");
        float xn = 0.f;
        for (int c = 0; c < 128; ++c) { float v = xl[c]; xn = fmaf(v, v, xn); }
        float best = 3.4e38f; int bi = 0x7fffffff;
        for (int j = 0; j < 16; ++j) {
            int k = j * 64 + lane;
            const float4* cr = reinterpret_cast<const float4*>(cb + (size_t)k * 128);
            float dot = 0.f;
            #pragma unroll
            for (int c4 = 0; c4 < 32; ++c4) {
                float4 bv = cr[c4];
                float4 xv = *reinterpret_cast<const float4*>(&xl[c4 * 4]);
                dot = fmaf(xv.x, bv.x, dot); dot = fmaf(xv.y, bv.y, dot);
                dot = fmaf(xv.z, bv.z, dot); dot = fmaf(xv.w, bv.w, dot);
            }
            float t1 = xn + bn[k];
            float s = fmaf(-2.0f, dot, t1);
            if (s < best || (s == best && k < bi)) { best = s; bi = k; }
        }
        #pragma unroll
        for (int m = 1; m < 64; m <<= 1) {
            float os = __shfl_xor(best, m, 64);
            int ok = __shfl_xor(bi, m, 64);
            if (os < best || (os == best && ok < bi)) { best = os; bi = ok; }
        }
        int k_new = __shfl(bi, 0, 64);
        patch_row(in, cb, idx_out, out_q, deltas, row, k_new, lane);
    }
}

// ---------- deterministic 2-stage loss reduce ----------
__global__ void loss_stage1(const float* __restrict__ partials, const float* __restrict__ deltas,
                            float* __restrict__ part2) {
    __shared__ float red_s[4];
    const int blk = blockIdx.x, tid = threadIdx.x;
    float s = 0.f;
    const float* dp = deltas + blk * 2048;
    for (int i = tid; i < 2048; i += 256) s += dp[i];
    if (tid < 32) s += partials[blk * 32 + tid];
    #pragma unroll
    for (int m = 1; m < 64; m <<= 1) s += __shfl_xor(s, m, 64);
    if ((tid & 63) == 0) red_s[tid >> 6] = s;
    __syncthreads();
    if (tid == 0) part2[blk] = red_s[0] + red_s[1] + red_s[2] + red_s[3];
}

__global__ void loss_stage2(const float* __restrict__ part2, float* __restrict__ out_loss) {
    const int tid = threadIdx.x;
    float s = part2[tid];
    #pragma unroll
    for (int m = 1; m < 64; m <<= 1) s += __shfl_xor(s, m, 64);
    if (tid == 0) out_loss[0] = 1.25f * (s / (float)NUMEL);
}

extern "C" void kernel_launch(void* const* d_in, const int* in_sizes, int n_in,
                              void* d_out, int out_size, void* d_ws, size_t ws_size,
                              hipStream_t stream) {
    (void)in_sizes; (void)n_in; (void)out_size; (void)ws_size;
    const float* in = (const float*)d_in[0];
    const float* cb = (const float*)d_in[1];
    float* out = (float*)d_out;

    char* ws = (char*)d_ws;
    float* bn       = (float*)(ws + 0);          //    4096 B
    u16*   Bpl      = (u16*)(ws + 4096);         //  524288 B
    uint2* smallL   = (uint2*)(ws + 528384);     //  262144 B (32768 x 8B)
    int*   fullL    = (int*)(ws + 790528);       //  131072 B (32768 x 4B)
    float* deltas   = (float*)(ws + 921600);     //  524288 B
    float* partials = (float*)(ws + 1445888);    //    8192 B
    float* part2    = (float*)(ws + 1454080);    //     256 B
    int*   cnts     = (int*)(ws + 1454336);      //     128 B

    float* idxf = out + NUMEL + 1;

    prep_cb_kernel<<<4, 256, 0, stream>>>(cb, bn, Bpl, cnts);
    gemm_fused_kernel<<<2048, 256, 0, stream>>>(in, cb, Bpl, bn, out, idxf,
                                                smallL, fullL, cnts, deltas, partials);
    small_rescore_kernel<<<1024, 256, 0, stream>>>(in, cb, bn, smallL, cnts, idxf, out, deltas);
    full_rescore_kernel<<<256, 256, 0, stream>>>(in, cb, bn, fullL, cnts, idxf, out, deltas);
    loss_stage1<<<64, 256, 0, stream>>>(partials, deltas, part2);
    loss_stage2<<<1, 64, 0, stream>>>(part2, out + NUMEL);
}

// Round 5
// 308.430 us; speedup vs baseline: 2.9367x; 1.2179x over previous
//
#include <hip/hip_runtime.h>

typedef unsigned short u16;
typedef __attribute__((ext_vector_type(8))) short bf16x8;
typedef __attribute__((ext_vector_type(4))) float f32x4;

#define K_CB  1024
#define N_ROWS 131072
#define NUMEL (N_ROWS * 128)
#define TAU2 6.0e-4f
#define SMALLCAP 32768
#define FULLCAP  32768

#define GLOAD16(gp, lp) __builtin_amdgcn_global_load_lds( \
    (const __attribute__((address_space(1))) unsigned int*)(gp), \
    (__attribute__((address_space(3))) unsigned int*)(lp), 16, 0, 0)

__device__ __forceinline__ u16 f2bf(float x) {
    union { float f; unsigned int u; } a; a.f = x;
    unsigned int r = a.u + 0x7fffu + ((a.u >> 16) & 1u);
    return (u16)(r >> 16);
}

// ---------- prep codebook: bn + slice-major bf16 HI plane ----------
// Bpl layout: [16 slices][1024 rows][8 bf16]
__global__ void prep_cb_kernel(const float* __restrict__ cb, float* __restrict__ bn,
                               u16* __restrict__ Bpl, int* __restrict__ cnts) {
    int k = blockIdx.x * 256 + threadIdx.x;
    if (blockIdx.x == 0 && threadIdx.x < 2) cnts[threadIdx.x] = 0;
    if (k >= K_CB) return;
    const float4* row4 = reinterpret_cast<const float4*>(cb) + k * 32;
    float s = 0.f;
    #pragma unroll
    for (int i = 0; i < 32; ++i) {
        float4 v = row4[i];
        s = fmaf(v.x, v.x, s); s = fmaf(v.y, v.y, s);
        s = fmaf(v.z, v.z, s); s = fmaf(v.w, v.w, s);
    }
    bn[k] = s;
    const float* rf = cb + k * 128;
    #pragma unroll
    for (int s8 = 0; s8 < 16; ++s8) {
        unsigned int hw[8];
        #pragma unroll
        for (int j = 0; j < 8; ++j) hw[j] = f2bf(rf[s8 * 8 + j]);
        uint4 H;
        H.x = hw[0] | (hw[1] << 16); H.y = hw[2] | (hw[3] << 16);
        H.z = hw[4] | (hw[5] << 16); H.w = hw[6] | (hw[7] << 16);
        *reinterpret_cast<uint4*>(&Bpl[((size_t)s8 * 1024 + k) * 8]) = H;
    }
}

// ---------- fused: transpose+split + hi-plane MFMA GEMM + argmin + candidates + quantize + loss ----------
__launch_bounds__(256, 3)
__global__ void gemm_fused_kernel(const float* __restrict__ in, const float* __restrict__ cb,
                                  const u16* __restrict__ Bpl, const float* __restrict__ bn,
                                  float* __restrict__ out_q, float* __restrict__ idx_out,
                                  uint2* __restrict__ smallL, int* __restrict__ fullL,
                                  int* __restrict__ cnts,
                                  float* __restrict__ deltas, float* __restrict__ partials) {
    __shared__ u16 A_s[16 * 64 * 8];      // 16384 B: [slice][row][8ch] hi plane
    __shared__ u16 Bb[2 * 4 * 256 * 8];   // 32768 B: dbuf x [slice-grp][256 rows][8ch]
    __shared__ float bn_s[K_CB];          // 4096 B
    __shared__ float red_s[4];

    const int tid = threadIdx.x;
    const int w = tid >> 6, lane = tid & 63, g4 = lane >> 4, l15 = lane & 15;
    const int blk = blockIdx.x, n0 = blk * 64;

    // B chunk-0 prefetch (slices 0..3, rows 0..255)
    #pragma unroll
    for (int i = 0; i < 4; ++i) {
        const u16* g = Bpl + (size_t)(w * 1024 + i * 64 + lane) * 8;
        GLOAD16(g, &Bb[(w * 256 + i * 64) * 8]);
    }
    for (int i = tid; i < K_CB; i += 256) bn_s[i] = bn[i];

    // A staging: gather [B,C,D,H,W] transpose, bf16-hi split in regs, b128 writes
    {
        const int base = (n0 >> 14) * (128 * 16384) + (n0 & 16383);
        #pragma unroll
        for (int i = 0; i < 4; ++i) {
            int p = tid + i * 256;            // 0..1023
            int n = p & 63, s = p >> 6;       // slice 0..15
            const float* g = in + base + (size_t)(s * 8) * 16384 + n;
            unsigned int pw[8];
            #pragma unroll
            for (int j = 0; j < 8; ++j) pw[j] = f2bf(g[(size_t)j * 16384]);
            uint4 H;
            H.x = pw[0] | (pw[1] << 16); H.y = pw[2] | (pw[3] << 16);
            H.z = pw[4] | (pw[5] << 16); H.w = pw[6] | (pw[7] << 16);
            *reinterpret_cast<uint4*>(&A_s[(s * 64 + n) * 8]) = H;
        }
    }
    __syncthreads();

    f32x4 acc[4][4];
    const f32x4 zz = {0.f, 0.f, 0.f, 0.f};
    #pragma unroll
    for (int mi = 0; mi < 4; ++mi)
        #pragma unroll
        for (int ni = 0; ni < 4; ++ni) acc[mi][ni] = zz;

    float b1[16], b2[16]; int i1[16];
    #pragma unroll
    for (int sl = 0; sl < 16; ++sl) { b1[sl] = 3.4e38f; b2[sl] = 3.4e38f; i1[sl] = 0; }

    // 16 k-steps: 4 cb-chunks x 4 K-slices (K=128 hi-plane only)
    #pragma unroll
    for (int t = 0; t < 16; ++t) {
        const int chunk = t >> 2, cc = t & 3, buf = t & 1;
        if (t < 15) {
            const int t2 = t + 1, chunk2 = t2 >> 2, cc2 = t2 & 3, nb = t2 & 1;
            #pragma unroll
            for (int i = 0; i < 4; ++i) {
                const u16* g = Bpl + (size_t)((cc2 * 4 + w) * 1024 + chunk2 * 256 + i * 64 + lane) * 8;
                GLOAD16(g, &Bb[((nb * 4 + w) * 256 + i * 64) * 8]);
            }
        }
        bf16x8 af[4], bfr[4];
        #pragma unroll
        for (int mi = 0; mi < 4; ++mi)
            af[mi] = *reinterpret_cast<const bf16x8*>(
                &A_s[((cc * 4 + g4) * 64 + mi * 16 + l15) * 8]);
        #pragma unroll
        for (int ni = 0; ni < 4; ++ni)
            bfr[ni] = *reinterpret_cast<const bf16x8*>(
                &Bb[((buf * 4 + g4) * 256 + w * 64 + ni * 16 + l15) * 8]);
        #pragma unroll
        for (int mi = 0; mi < 4; ++mi)
            #pragma unroll
            for (int ni = 0; ni < 4; ++ni)
                acc[mi][ni] = __builtin_amdgcn_mfma_f32_16x16x32_bf16(af[mi], bfr[ni], acc[mi][ni], 0, 0, 0);

        if (cc == 3) {
            const int cb0s = chunk * 256;
            #pragma unroll
            for (int mi = 0; mi < 4; ++mi) {
                #pragma unroll
                for (int ni = 0; ni < 4; ++ni) {
                    int n = cb0s + w * 64 + ni * 16 + l15;
                    float bnv = bn_s[n];
                    #pragma unroll
                    for (int r = 0; r < 4; ++r) {
                        float s = fmaf(-2.0f, acc[mi][ni][r], bnv);
                        int sl = mi * 4 + r;
                        if (s < b1[sl]) { b2[sl] = b1[sl]; b1[sl] = s; i1[sl] = n; }
                        else if (s < b2[sl]) b2[sl] = s;
                    }
                    acc[mi][ni] = zz;
                }
            }
        }
        __syncthreads();
    }

    // ---- overlay post-loop arrays onto Bb (dead after last barrier) ----
    float* m_b1   = (float*)Bb;          // [4][64]
    float* m_b2   = m_b1 + 256;          // [4][64]
    int*   m_i1   = (int*)(m_b2 + 256);  // [4][64]
    int*   idx_s  = m_i1 + 256;          // [64]
    float* gmin_s = (float*)(idx_s + 64);
    int*   flg_s  = (int*)(gmin_s + 64);
    int*   ccnt_s = flg_s + 64;
    int*   fb_s   = ccnt_s + 64;
    int*   cand_s = fb_s + 64;           // [64][4]

    // merge across 16 l15 lanes (per-lane b1/b2/i1 stay intact for emission)
    #pragma unroll
    for (int sl = 0; sl < 16; ++sl) {
        float v1 = b1[sl], v2 = b2[sl]; int ix = i1[sl];
        #pragma unroll
        for (int m = 1; m < 16; m <<= 1) {
            float o1 = __shfl_xor(v1, m, 64);
            int   oi = __shfl_xor(ix, m, 64);
            float o2 = __shfl_xor(v2, m, 64);
            if (o1 < v1 || (o1 == v1 && oi < ix)) { v2 = fminf(v1, o2); v1 = o1; ix = oi; }
            else v2 = fminf(v2, o1);
        }
        if (l15 == 0) {
            int mi = sl >> 2, r = sl & 3;
            int rl = mi * 16 + g4 * 4 + r;
            m_b1[w * 64 + rl] = v1; m_b2[w * 64 + rl] = v2; m_i1[w * 64 + rl] = ix;
        }
    }
    __syncthreads();
    if (tid < 64) {
        float v1 = m_b1[tid], v2 = m_b2[tid]; int ix = m_i1[tid];
        #pragma unroll
        for (int wv = 1; wv < 4; ++wv) {
            float o1 = m_b1[wv * 64 + tid], o2 = m_b2[wv * 64 + tid]; int oi = m_i1[wv * 64 + tid];
            if (o1 < v1 || (o1 == v1 && oi < ix)) { v2 = fminf(v1, o2); v1 = o1; ix = oi; }
            else v2 = fminf(v2, o1);
        }
        idx_s[tid] = ix;
        idx_out[n0 + tid] = (float)ix;
        deltas[n0 + tid] = 0.f;
        gmin_s[tid] = v1;
        flg_s[tid] = (v2 - v1 <= TAU2) ? 1 : 0;
        ccnt_s[tid] = 0;
        fb_s[tid] = 0;
    }
    __syncthreads();

    // candidate emission: each (w,l15) bucket offers its best if within TAU2 of row min
    #pragma unroll
    for (int sl = 0; sl < 16; ++sl) {
        int mi = sl >> 2, r = sl & 3;
        int rl = mi * 16 + g4 * 4 + r;
        if (flg_s[rl]) {
            float g = gmin_s[rl];
            if (b1[sl] - g <= TAU2) {
                int p = atomicAdd(&ccnt_s[rl], 1);
                if (p < 4) cand_s[rl * 4 + p] = i1[sl]; else fb_s[rl] = 1;
            }
            if (b2[sl] - g <= TAU2) fb_s[rl] = 1;  // can't bound 3rd-in-bucket
        }
    }
    __syncthreads();
    if (tid < 64 && flg_s[tid]) {
        int nc = ccnt_s[tid];
        int row = n0 + tid;
        if (!fb_s[tid] && nc >= 2) {
            int p = atomicAdd(&cnts[0], 1);
            if (p < SMALLCAP) {
                unsigned long long key = (unsigned long long)row |
                                         ((unsigned long long)nc << 20);
                for (int j = 0; j < nc; ++j)
                    key |= (unsigned long long)(cand_s[tid * 4 + j] & 1023) << (24 + 10 * j);
                uint2 rec; rec.x = (unsigned)key; rec.y = (unsigned)(key >> 32);
                smallL[p] = rec;
            } else {
                int q = atomicAdd(&cnts[1], 1);
                if (q < FULLCAP) fullL[q] = row;
            }
        } else if (fb_s[tid]) {
            int q = atomicAdd(&cnts[1], 1);
            if (q < FULLCAP) fullL[q] = row;
        }
    }
    __syncthreads();

    // fused quantize + straight-through + loss partial (linear flat layout)
    float acc_l = 0.f;
    const float4* cb4 = reinterpret_cast<const float4*>(cb);
    const float4* in4 = reinterpret_cast<const float4*>(in);
    float4* out4 = reinterpret_cast<float4*>(out_q);
    #pragma unroll
    for (int i = 0; i < 8; ++i) {
        int idx = tid + i * 256;
        int row = idx >> 5;
        int c4 = idx & 31;
        int kq = idx_s[row];
        float4 q = cb4[kq * 32 + c4];
        float4 x = in4[(size_t)(n0 + row) * 32 + c4];
        float4 d, o;
        d.x = q.x - x.x; d.y = q.y - x.y; d.z = q.z - x.z; d.w = q.w - x.w;
        o.x = x.x + d.x; o.y = x.y + d.y; o.z = x.z + d.z; o.w = x.w + d.w;
        out4[(size_t)(n0 + row) * 32 + c4] = o;
        acc_l += d.x * d.x; acc_l += d.y * d.y; acc_l += d.z * d.z; acc_l += d.w * d.w;
    }
    #pragma unroll
    for (int m = 1; m < 64; m <<= 1) acc_l += __shfl_xor(acc_l, m, 64);
    if ((tid & 63) == 0) red_s[tid >> 6] = acc_l;
    __syncthreads();
    if (tid == 0) partials[blk] = red_s[0] + red_s[1] + red_s[2] + red_s[3];
}

// ---------- common patch helper (wave-level) ----------
__device__ __forceinline__ void patch_row(const float* __restrict__ in,
                                          const float* __restrict__ cb,
                                          float* __restrict__ idx_out,
                                          float* __restrict__ out_q,
                                          float* __restrict__ deltas,
                                          int row, int k_new, int lane) {
    int k_old = (int)idx_out[row];
    if (k_new == k_old) return;
    if (lane == 0) idx_out[row] = (float)k_new;
    float dd = 0.f;
    if (lane < 32) {
        const float4* in4 = reinterpret_cast<const float4*>(in);
        const float4* cb4 = reinterpret_cast<const float4*>(cb);
        float4* out4 = reinterpret_cast<float4*>(out_q);
        float4 x = in4[(size_t)row * 32 + lane];
        float4 qn = cb4[(size_t)k_new * 32 + lane];
        float4 qo = cb4[(size_t)k_old * 32 + lane];
        float4 dn, dl, o;
        dn.x = qn.x - x.x; dn.y = qn.y - x.y; dn.z = qn.z - x.z; dn.w = qn.w - x.w;
        o.x = x.x + dn.x; o.y = x.y + dn.y; o.z = x.z + dn.z; o.w = x.w + dn.w;
        out4[(size_t)row * 32 + lane] = o;
        dl.x = qo.x - x.x; dl.y = qo.y - x.y; dl.z = qo.z - x.z; dl.w = qo.w - x.w;
        dd = dn.x * dn.x + dn.y * dn.y + dn.z * dn.z + dn.w * dn.w
           - (dl.x * dl.x + dl.y * dl.y + dl.z * dl.z + dl.w * dl.w);
    }
    #pragma unroll
    for (int m = 1; m < 64; m <<= 1) dd += __shfl_xor(dd, m, 64);
    if (lane == 0) deltas[row] = dd;
}

// ---------- small rescore: one wave per record, <=4 candidates, exact arithmetic ----------
__global__ void small_rescore_kernel(const float* __restrict__ in, const float* __restrict__ cb,
                                     const float* __restrict__ bn, const uint2* __restrict__ recs,
                                     const int* __restrict__ cnts, float* __restrict__ idx_out,
                                     float* __restrict__ out_q, float* __restrict__ deltas) {
    __shared__ float xls[4][128];
    const int tid = threadIdx.x, wv = tid >> 6, lane = tid & 63;
    int ns = cnts[0]; if (ns > SMALLCAP) ns = SMALLCAP;
    float* xl = xls[wv];
    for (int f = blockIdx.x * 4 + wv; f < ns; f += gridDim.x * 4) {
        uint2 rc = recs[f];
        unsigned long long key = ((unsigned long long)rc.y << 32) | (unsigned long long)rc.x;
        int row = (int)(key & 131071ull);
        int nc = (int)((key >> 20) & 7ull);
        int ck = (lane < 4) ? (int)((key >> (24 + 10 * lane)) & 1023ull) : 0;
        const float* bp = in + (size_t)(row >> 14) * 2097152 + (row & 16383);
        xl[2 * lane]     = bp[(size_t)(2 * lane) * 16384];
        xl[2 * lane + 1] = bp[(size_t)(2 * lane + 1) * 16384];
        asm volatile("s_waitcnt vmcnt(0) lgkmcnt(0)" ::: "memory");
        float xn = 0.f;
        for (int c = 0; c < 128; ++c) { float v = xl[c]; xn = fmaf(v, v, xn); }
        float s = 3.4e38f; int kk = 0x7fffffff;
        if (lane < nc) {
            const float4* cr = reinterpret_cast<const float4*>(cb + (size_t)ck * 128);
            float dot = 0.f;
            #pragma unroll
            for (int c4 = 0; c4 < 32; ++c4) {
                float4 bv = cr[c4];
                float4 xv = *reinterpret_cast<const float4*>(&xl[c4 * 4]);
                dot = fmaf(xv.x, bv.x, dot); dot = fmaf(xv.y, bv.y, dot);
                dot = fmaf(xv.z, bv.z, dot); dot = fmaf(xv.w, bv.w, dot);
            }
            float t1 = xn + bn[ck];
            s = fmaf(-2.0f, dot, t1);
            kk = ck;
        }
        #pragma unroll
        for (int m = 1; m < 4; m <<= 1) {
            float os = __shfl_xor(s, m, 64);
            int ok = __shfl_xor(kk, m, 64);
            if (os < s || (os == s && ok < kk)) { s = os; kk = ok; }
        }
        int k_new = __shfl(kk, 0, 64);
        patch_row(in, cb, idx_out, out_q, deltas, row, k_new, lane);
    }
}

// ---------- full rescore fallback: one wave per row, exact arithmetic ----------
__global__ void full_rescore_kernel(const float* __restrict__ in, const float* __restrict__ cb,
                                    const float* __restrict__ bn, const int* __restrict__ fullL,
                                    const int* __restrict__ cnts, float* __restrict__ idx_out,
                                    float* __restrict__ out_q, float* __restrict__ deltas) {
    __shared__ float xls[4][128];
    const int tid = threadIdx.x, wv = tid >> 6, lane = tid & 63;
    int nf = cnts[1]; if (nf > FULLCAP) nf = FULLCAP;
    float* xl = xls[wv];
    for (int f = blockIdx.x * 4 + wv; f < nf; f += gridDim.x * 4) {
        int row = fullL[f];
        const float* bp = in + (size_t)(row >> 14) * 2097152 + (row & 16383);
        xl[2 * lane]     = bp[(size_t)(2 * lane) * 16384];
        xl[2 * lane + 1] = bp[(size_t)(2 * lane + 1) * 16384];
        asm volatile("s_waitcnt vmcnt(0) lgkmcnt(0)" ::: "memory");
        float xn = 0.f;
        for (int c = 0; c < 128; ++c) { float v = xl[c]; xn = fmaf(v, v, xn); }
        float best = 3.4e38f; int bi = 0x7fffffff;
        for (int j = 0; j < 16; ++j) {
            int k = j * 64 + lane;
            const float4* cr = reinterpret_cast<const float4*>(cb + (size_t)k * 128);
            float dot = 0.f;
            #pragma unroll
            for (int c4 = 0; c4 < 32; ++c4) {
                float4 bv = cr[c4];
                float4 xv = *reinterpret_cast<const float4*>(&xl[c4 * 4]);
                dot = fmaf(xv.x, bv.x, dot); dot = fmaf(xv.y, bv.y, dot);
                dot = fmaf(xv.z, bv.z, dot); dot = fmaf(xv.w, bv.w, dot);
            }
            float t1 = xn + bn[k];
            float s = fmaf(-2.0f, dot, t1);
            if (s < best || (s == best && k < bi)) { best = s; bi = k; }
        }
        #pragma unroll
        for (int m = 1; m < 64; m <<= 1) {
            float os = __shfl_xor(best, m, 64);
            int ok = __shfl_xor(bi, m, 64);
            if (os < best || (os == best && ok < bi)) { best = os; bi = ok; }
        }
        int k_new = __shfl(bi, 0, 64);
        patch_row(in, cb, idx_out, out_q, deltas, row, k_new, lane);
    }
}

// ---------- deterministic 2-stage loss reduce ----------
__global__ void loss_stage1(const float* __restrict__ partials, const float* __restrict__ deltas,
                            float* __restrict__ part2) {
    __shared__ float red_s[4];
    const int blk = blockIdx.x, tid = threadIdx.x;
    float s = 0.f;
    const float* dp = deltas + blk * 2048;
    for (int i = tid; i < 2048; i += 256) s += dp[i];
    if (tid < 32) s += partials[blk * 32 + tid];
    #pragma unroll
    for (int m = 1; m < 64; m <<= 1) s += __shfl_xor(s, m, 64);
    if ((tid & 63) == 0) red_s[tid >> 6] = s;
    __syncthreads();
    if (tid == 0) part2[blk] = red_s[0] + red_s[1] + red_s[2] + red_s[3];
}

__global__ void loss_stage2(const float* __restrict__ part2, float* __restrict__ out_loss) {
    const int tid = threadIdx.x;
    float s = part2[tid];
    #pragma unroll
    for (int m = 1; m < 64; m <<= 1) s += __shfl_xor(s, m, 64);
    if (tid == 0) out_loss[0] = 1.25f * (s / (float)NUMEL);
}

extern "C" void kernel_launch(void* const* d_in, const int* in_sizes, int n_in,
                              void* d_out, int out_size, void* d_ws, size_t ws_size,
                              hipStream_t stream) {
    (void)in_sizes; (void)n_in; (void)out_size; (void)ws_size;
    const float* in = (const float*)d_in[0];
    const float* cb = (const float*)d_in[1];
    float* out = (float*)d_out;

    char* ws = (char*)d_ws;
    float* bn       = (float*)(ws + 0);          //    4096 B
    u16*   Bpl      = (u16*)(ws + 4096);         //  262144 B (hi plane only)
    uint2* smallL   = (uint2*)(ws + 528384);     //  262144 B
    int*   fullL    = (int*)(ws + 790528);       //  131072 B
    float* deltas   = (float*)(ws + 921600);     //  524288 B
    float* partials = (float*)(ws + 1445888);    //    8192 B
    float* part2    = (float*)(ws + 1454080);    //     256 B
    int*   cnts     = (int*)(ws + 1454336);      //     128 B

    float* idxf = out + NUMEL + 1;

    prep_cb_kernel<<<4, 256, 0, stream>>>(cb, bn, Bpl, cnts);
    gemm_fused_kernel<<<2048, 256, 0, stream>>>(in, cb, Bpl, bn, out, idxf,
                                                smallL, fullL, cnts, deltas, partials);
    small_rescore_kernel<<<1024, 256, 0, stream>>>(in, cb, bn, smallL, cnts, idxf, out, deltas);
    full_rescore_kernel<<<256, 256, 0, stream>>>(in, cb, bn, fullL, cnts, idxf, out, deltas);
    loss_stage1<<<64, 256, 0, stream>>>(partials, deltas, part2);
    loss_stage2<<<1, 64, 0, stream>>>(part2, out + NUMEL);
}